// Round 5
// baseline (116.311 us; speedup 1.0000x reference)
//
#include <hip/hip_runtime.h>
#include <hip/hip_bf16.h>
#include <math.h>

#define S 16
#define C 8
#define NB 64   // batch
#define L 4096
#define K 64    // chunks per batch
#define LC 64   // steps per chunk
#define NP 32   // chunk-pairs per batch (in-block combined)

#define SLOT 324  // bf16 elems per matrix slot = 648 B (162 banks % 32 == 2 -> quad-distinct slot bases)
#define RS 20     // row stride in elems (40 B -> conflict-free row-major scatters)
#define XSS 10    // xs floats per step (40 B stride -> 2-way-max bank aliasing on A-frag reads)

typedef __attribute__((ext_vector_type(8))) short bf16x8;
typedef __attribute__((ext_vector_type(4))) short bf16x4;
typedef __attribute__((ext_vector_type(4))) float f32x4;
typedef unsigned long long ull;

// ws byte layout:
#define WS_CLOG 0       // f32[4096] (16 KB)
#define WS_CP   16384   // bf16 pairP[64*32][256]; even pair row-major, odd [col][row]

__device__ __forceinline__ float hsig(float x) {
    return x / (1.0f + fabsf(x)) * 0.5f + 0.5f;
}
// Native RNE bf16 converts (v_cvt_pk_bf16_f32).
__device__ __forceinline__ unsigned int f2bf2(float a, float b) {
    __hip_bfloat162 h = __float22bfloat162_rn(make_float2(a, b));
    unsigned int u; __builtin_memcpy(&u, &h, 4); return u;
}
__device__ __forceinline__ unsigned short f2bf(float f) {
    __hip_bfloat16 h = __float2bfloat16(f);
    unsigned short u; __builtin_memcpy(&u, &h, 2); return u;
}

// 16x16x16 bf16 MFMA. Fallback: zero-extend BOTH operands with the SAME
// K-permutation into the x32 op — dead products are 0*0, result identical.
__device__ __forceinline__ f32x4 mfma16(bf16x4 a, bf16x4 b, f32x4 c) {
#if __has_builtin(__builtin_amdgcn_mfma_f32_16x16x16bf16_1k)
    return __builtin_amdgcn_mfma_f32_16x16x16bf16_1k(a, b, c, 0, 0, 0);
#else
    bf16x8 a8 = {a[0], a[1], a[2], a[3], 0, 0, 0, 0};
    bf16x8 b8 = {b[0], b[1], b[2], b[3], 0, 0, 0, 0};
    return __builtin_amdgcn_mfma_f32_16x16x32_bf16(a8, b8, c, 0, 0, 0);
#endif
}

// A-frag from a row-major RS-stride slot, or B-frag from a col-major slot:
// both are elems [col*RS + quad*4 .. +3]. 8 B aligned (RS*2=40, SLOT*2=648).
__device__ __forceinline__ bf16x4 ldfrag4(const unsigned short* base, int lane) {
    return *(const bf16x4*)(base + (lane & 15) * RS + (lane >> 4) * 4);
}
// Same from a packed global 16x16 matrix (stride 16).
__device__ __forceinline__ bf16x4 ldfrag_g4(const unsigned short* base, int lane) {
    return *(const bf16x4*)(base + (lane & 15) * 16 + (lane >> 4) * 4);
}
// D-fragment -> B-fragment is the identity lane mapping for 16x16 shapes.
__device__ __forceinline__ bf16x4 cvt4(f32x4 d) {
    union { unsigned int u[2]; bf16x4 v; } cv;
    cv.u[0] = f2bf2(d[0], d[1]);
    cv.u[1] = f2bf2(d[2], d[3]);
    return cv.v;
}
__device__ __forceinline__ void store16(unsigned short* slot, f32x4 d, int lane, bool odd) {
    int col = lane & 15, quad = lane >> 4;
    if (odd) {  // col-major (B-ready): packed 8 B store
        ull pk = (ull)f2bf2(d[0], d[1]) | ((ull)f2bf2(d[2], d[3]) << 32);
        *(ull*)(slot + col * RS + quad * 4) = pk;
    } else {    // row-major (A-ready): 4-elem scatter
#pragma unroll
        for (int r = 0; r < 4; r++) slot[(quad * 4 + r) * RS + col] = f2bf(d[r]);
    }
}

// lv2..root of a 32->1 tree; lv1 even results row-major in LDS at slots 8w and
// 8w+4, lv1 odd results reg-fed (B1a, B1b; D==B layout). ONE barrier; lv4+root
// on wave 0 only (root is only consumed by w0). Waves 1-3 return garbage and
// are free to run ahead — callers must not let them write slots before their
// next __syncthreads (chunk: next softmax barrier; reduce: they exit).
__device__ __forceinline__ f32x4 tree_upper(unsigned short* slots, int lane, int w,
                                            bf16x4 B1a, bf16x4 B1b) {
    f32x4 z = {0.f, 0.f, 0.f, 0.f};
    f32x4 dA = mfma16(ldfrag4(slots + (8 * w) * SLOT, lane), B1a, z);   // lv2 prod 2w
    store16(slots + (8 * w) * SLOT, dA, lane, false);                   // -> A of lv3
    f32x4 dB = mfma16(ldfrag4(slots + (8 * w + 4) * SLOT, lane), B1b, z); // lv2 prod 2w+1
    f32x4 d3 = mfma16(ldfrag4(slots + (8 * w) * SLOT, lane), cvt4(dB), z); // lv3 prod w
    store16(slots + (8 * w) * SLOT, d3, lane, w & 1);  // w0:s0 rm, w1:s8 cm, w2:s16 rm, w3:s24 cm
    __syncthreads();
    f32x4 root = z;
    if (w == 0) {
        f32x4 d4a = mfma16(ldfrag4(slots, lane), ldfrag4(slots + 8 * SLOT, lane), z);
        f32x4 d4b = mfma16(ldfrag4(slots + 16 * SLOT, lane), ldfrag4(slots + 24 * SLOT, lane), z);
        store16(slots, d4a, lane, false);              // rm -> A of root (same-wave, lgkm-ordered)
        root = mfma16(ldfrag4(slots, lane), cvt4(d4b), z);
    }
    return root;
}

// Two chunks per block, combined in-block to ONE pair matrix. NO prep kernel:
// each block normalizes T into LDS (TnL, aliasing slots — all TnL reads finish
// before each wave's softmax, whose barrier precedes the first slot write) and
// each lane computes exactly its own 64 TTT entries (bfr frags) via VALU.
__global__ void __launch_bounds__(256) chunk_kernel(const float* __restrict__ logx,
                                                    const float* __restrict__ invh_T,
                                                    unsigned char* __restrict__ wsb) {
    __shared__ __align__(16) unsigned char smem[32 * SLOT * 2];  // 20736 B (slots | TnL alias)
    __shared__ __align__(16) float xs[LC * XSS];                 // 2560 B normalized probs
    __shared__ float clpart[4];

    int tid = threadIdx.x, lane = tid & 63, w = tid >> 6;
    int col = lane & 15, quad = lane >> 4;
    int pi = blockIdx.x, b = blockIdx.y;
    int chunk0 = 2 * pi;

    // Both chunks' x tiles: issue global loads first (latency hidden under Tn build).
    const float* xg = logx + ((size_t)b * L + (size_t)chunk0 * LC) * C;
    float2 vv[2];
    vv[0] = *(const float2*)(xg + 2 * tid);            // coalesced 8 B/lane
    vv[1] = *(const float2*)(xg + LC * C + 2 * tid);

    // TnL[(p*8+c)*16 + n] = hyperbolic_softmax(invh_T) rows. Thread tid owns
    // half-row: row r=tid>>1 (=(p*8+c)), n in [8(tid&1), 8(tid&1)+8). Row-sum
    // via one shfl_xor with the partner lane. Fully coalesced 32 B/lane.
    float* TnL = (float*)smem;
    {
        const float4* tg = (const float4*)invh_T + tid * 2;
        float4 aa = tg[0], bb = tg[1];
        float va[8] = {aa.x, aa.y, aa.z, aa.w, bb.x, bb.y, bb.z, bb.w};
        float s = 0.f;
#pragma unroll
        for (int i = 0; i < 8; i++) { va[i] = hsig(va[i]); s += va[i]; }
        s += __shfl_xor(s, 1);
        float inv = 1.f / s;
        float4 o0 = {va[0] * inv, va[1] * inv, va[2] * inv, va[3] * inv};
        float4 o1 = {va[4] * inv, va[5] * inv, va[6] * inv, va[7] * inv};
        ((float4*)TnL)[tid * 2] = o0;
        ((float4*)TnL)[tid * 2 + 1] = o1;
    }
    __syncthreads();

    // B-frags for the pair-product construct, computed in-lane:
    // bfr[jj][kk][j] = f2bf( sum_k TnL[((4w+jj)*8 + kk*4+quad)*16 + k]
    //                              * TnL[(k*8 + j)*16 + col] )
    // (identical values/order to the old prep TTT). Two kk passes keep VGPR low.
    // LDS reads are broadcast/conflict-free (16 distinct addrs x 4-way same-addr).
    bf16x8 bfr[4][2];
#pragma unroll
    for (int kk = 0; kk < 2; kk++) {
        float acc[4][8];
#pragma unroll
        for (int jj = 0; jj < 4; jj++)
#pragma unroll
            for (int j = 0; j < 8; j++) acc[jj][j] = 0.f;
#pragma unroll
        for (int k = 0; k < 16; k++) {
            float bc[8];
#pragma unroll
            for (int j = 0; j < 8; j++) bc[j] = TnL[(k * 8 + j) * 16 + col];
#pragma unroll
            for (int jj = 0; jj < 4; jj++) {
                float ar = TnL[((4 * w + jj) * 8 + kk * 4 + quad) * 16 + k];
#pragma unroll
                for (int j = 0; j < 8; j++) acc[jj][j] += ar * bc[j];
            }
        }
#pragma unroll
        for (int jj = 0; jj < 4; jj++) {
            union { unsigned int u[4]; bf16x8 v8; } cv;
            cv.u[0] = f2bf2(acc[jj][0], acc[jj][1]);
            cv.u[1] = f2bf2(acc[jj][2], acc[jj][3]);
            cv.u[2] = f2bf2(acc[jj][4], acc[jj][5]);
            cv.u[3] = f2bf2(acc[jj][6], acc[jj][7]);
            bfr[jj][kk] = cv.v8;
        }
    }

    unsigned short* slots = (unsigned short*)smem;
    f32x4 root0, root1;
#pragma unroll
    for (int ch = 0; ch < 2; ch++) {
        int chunk = chunk0 + ch;

        // Per-step softmax: thread tid owns channels {2(tid&3), 2(tid&3)+1} of
        // step tid>>2; 4-lane-group shuffle reduce.
        float2 v = vv[ch];
        float m = fmaxf(v.x, v.y);
        m = fmaxf(m, __shfl_xor(m, 1));
        m = fmaxf(m, __shfl_xor(m, 2));
        float e0 = __expf(v.x - m), e1 = __expf(v.y - m);
        float s = e0 + e1;
        s += __shfl_xor(s, 1);
        s += __shfl_xor(s, 2);
        float inv = 1.0f / s;
        *(float2*)(xs + (tid >> 2) * XSS + 2 * (tid & 3)) = make_float2(e0 * inv, e1 * inv);
        float lx = ((tid & 3) == 0) ? (m + __logf(s)) : 0.f;   // one contribution per step
#pragma unroll
        for (int d = 1; d < 64; d <<= 1) lx += __shfl_xor(lx, d);  // wave partial (16 steps)
        if (lane == 0) clpart[w] = lx;
        __syncthreads();   // also orders all TnL reads before first slot write (ch 0)
        if (tid == 0)
            ((float*)(wsb + WS_CLOG))[b * K + chunk] = clpart[0] + clpart[1] + clpart[2] + clpart[3];

        // A-frags: y[i][cc'] = xn[2i][c]*xn[2i+1][c'].
        bf16x8 afr[2][2];
#pragma unroll
        for (int mt = 0; mt < 2; mt++) {
            int i2 = 2 * (mt * 16 + col);
            const float2* x1p = (const float2*)(xs + (i2 + 1) * XSS);
            float2 q0 = x1p[0], q1 = x1p[1], q2 = x1p[2], q3 = x1p[3];
#pragma unroll
            for (int kk = 0; kk < 2; kk++) {
                float x0 = xs[i2 * XSS + kk * 4 + quad];
                union { unsigned int u[4]; bf16x8 v8; } cv;
                cv.u[0] = f2bf2(x0 * q0.x, x0 * q0.y);
                cv.u[1] = f2bf2(x0 * q1.x, x0 * q1.y);
                cv.u[2] = f2bf2(x0 * q2.x, x0 * q2.y);
                cv.u[3] = f2bf2(x0 * q3.x, x0 * q3.y);
                afr[mt][kk] = cv.v8;
            }
        }

        // Pair-product construct -> slots 0..31 (parity i&1: even rm / odd cm).
#pragma unroll
        for (int mt = 0; mt < 2; mt++)
#pragma unroll
            for (int jj = 0; jj < 4; jj++) {
                f32x4 acc = {0.f, 0.f, 0.f, 0.f};
#pragma unroll
                for (int kk = 0; kk < 2; kk++)
                    acc = __builtin_amdgcn_mfma_f32_16x16x32_bf16(afr[mt][kk], bfr[jj][kk], acc, 0, 0, 0);
                int t = 4 * w + jj;  // = p
#pragma unroll
                for (int r = 0; r < 4; r++) {
                    int i = mt * 16 + quad * 4 + r;
                    int off = (i & 1) ? (col * RS + t) : (t * RS + col);
                    slots[i * SLOT + off] = f2bf(acc[r]);
                }
            }
        __syncthreads();

        // lv1: wave w owns products i in [4w,4w+4). Even i -> LDS (A of lv2),
        // odd i -> registers (B of lv2, D==B layout).
        bf16x4 B1[2];
        {
            f32x4 z = {0.f, 0.f, 0.f, 0.f};
#pragma unroll
            for (int i2 = 0; i2 < 4; i2++) {
                int i = 4 * w + i2;
                f32x4 d = mfma16(ldfrag4(slots + (2 * i) * SLOT, lane),
                                 ldfrag4(slots + (2 * i + 1) * SLOT, lane), z);
                if (i2 & 1) B1[i2 >> 1] = cvt4(d);
                else store16(slots + (2 * i) * SLOT, d, lane, false);
            }
        }
        f32x4 root = tree_upper(slots, lane, w, B1[0], B1[1]);  // valid on w0 only
        if (ch == 0) root0 = root; else root1 = root;
    }

    // In-block pair combine (w0 only; waves 1-3 have exited their slot reads).
    if (w == 0) {
        f32x4 z = {0.f, 0.f, 0.f, 0.f};
        store16(slots, root0, lane, false);            // rm -> A (same-wave ordered)
        f32x4 fin = mfma16(ldfrag4(slots, lane), cvt4(root1), z);
        unsigned short* cp = (unsigned short*)(wsb + WS_CP) + ((size_t)b * NP + pi) * 256;
        if (pi & 1) {
            ull pk = (ull)f2bf2(fin[0], fin[1]) | ((ull)f2bf2(fin[2], fin[3]) << 32);
            *(ull*)(cp + col * 16 + quad * 4) = pk;
        } else {
#pragma unroll
            for (int r = 0; r < 4; r++) cp[(quad * 4 + r) * 16 + col] = f2bf(fin[r]);
        }
    }
}

__global__ void __launch_bounds__(256) reduce_kernel(unsigned char* __restrict__ wsb,
                                                     const float* __restrict__ invh_init,
                                                     const float* __restrict__ invh_acc,
                                                     float* __restrict__ out) {
    __shared__ __align__(16) unsigned short slots[32 * SLOT];  // 20736 B
    int tid = threadIdx.x, lane = tid & 63, w = tid >> 6;
    int col = lane & 15, quad = lane >> 4;
    int b = blockIdx.x;

    const unsigned short* cpb = (const unsigned short*)(wsb + WS_CP) + (size_t)b * NP * 256;
    // lv0': 4 products/wave of global pairs (even pair rm -> A, odd cm -> B).
    // Even i2 -> slots 8w, 8w+4 rm; odd i2 -> regs (B of lv2). Feeds tree_upper
    // directly (same-wave write->read is lgkm-ordered, no barrier needed).
    bf16x4 B1r[2];
    {
        f32x4 z = {0.f, 0.f, 0.f, 0.f};
#pragma unroll
        for (int i2 = 0; i2 < 4; i2++) {
            int i = 4 * w + i2;
            f32x4 d = mfma16(ldfrag_g4(cpb + (size_t)(2 * i) * 256, lane),
                             ldfrag_g4(cpb + (size_t)(2 * i + 1) * 256, lane), z);
            if (i2 & 1) B1r[i2 >> 1] = cvt4(d);
            else store16(slots + (2 * i) * SLOT, d, lane, false);
        }
    }
    f32x4 troot = tree_upper(slots, lane, w, B1r[0], B1r[1]);

    if (w == 0) {
        // init/acc terms computed from raw inputs (was prepall's job).
        float si = 0.f;
#pragma unroll
        for (int k = 0; k < S; k++) si += hsig(invh_init[k]);
        float isi = 1.f / si;
        float part = 0.f;
#pragma unroll
        for (int r = 0; r < 4; r++) part += hsig(invh_init[quad * 4 + r]) * isi * troot[r];
        part += __shfl_xor(part, 16);
        part += __shfl_xor(part, 32);
        float lp = logf(fmaxf(part, 0.f) + 1e-30f) + logf(hsig(invh_acc[col]));
        float mx = lp;
#pragma unroll
        for (int d = 1; d < 16; d <<= 1) mx = fmaxf(mx, __shfl_xor(mx, d));
        float a2 = isfinite(mx) ? mx : 0.0f;  // jax.nn.logsumexp semantics
        float sm = expf(lp - a2);
#pragma unroll
        for (int d = 1; d < 16; d <<= 1) sm += __shfl_xor(sm, d);
        float cl = ((const float*)(wsb + WS_CLOG))[b * K + lane];
#pragma unroll
        for (int d = 1; d < 64; d <<= 1) cl += __shfl_xor(cl, d);
        if (lane == 0) out[b] = logf(sm) + a2 + cl;
    }
}

extern "C" void kernel_launch(void* const* d_in, const int* in_sizes, int n_in,
                              void* d_out, int out_size, void* d_ws, size_t ws_size,
                              hipStream_t stream) {
    const float* logx = (const float*)d_in[0];   // (B, L, C) f32
    const float* init = (const float*)d_in[1];   // (S,) f32
    const float* T    = (const float*)d_in[2];   // (S, C, S) f32
    const float* acc  = (const float*)d_in[3];   // (S,) f32
    unsigned char* wsb = (unsigned char*)d_ws;
    float* out = (float*)d_out;

    chunk_kernel<<<dim3(NP, NB), 256, 0, stream>>>(logx, T, wsb);
    reduce_kernel<<<NB, 256, 0, stream>>>(wsb, init, acc, out);
}

// Round 6
// 81.509 us; speedup vs baseline: 1.4270x; 1.4270x over previous
//
#include <hip/hip_runtime.h>
#include <hip/hip_bf16.h>
#include <math.h>

#define S 16
#define C 8
#define NB 64   // batch
#define L 4096
#define K 64    // chunks per batch
#define LC 64   // steps per chunk
#define NQ 16   // chunk-quads per batch (4 chunks combined in-block)

#define SLOT 320  // bf16 elems per matrix slot (16 rows x RS); base alignment irrelevant
#define RS 20     // row stride in elems (40 B -> conflict-free row-major scatters)
#define XSS 10    // xs floats per step (40 B stride -> 2-way-max bank aliasing on A-frag reads)

typedef __attribute__((ext_vector_type(8))) short bf16x8;
typedef __attribute__((ext_vector_type(4))) short bf16x4;
typedef __attribute__((ext_vector_type(4))) float f32x4;
typedef unsigned long long ull;

// ws byte layout:
#define WS_INIT 0       // f32[16]
#define WS_ACC  64      // f32[16]
#define WS_CLOG 512     // f32[4096] (16 KB)
#define WS_TTT  16896   // bf16 TTT[(p*16+n)][cc'=64] (32 KB), B-frag-ready
#define WS_CP   49664   // bf16 quadP[64*16][256]; even quad row-major, odd [col][row]

__device__ __forceinline__ float hsig(float x) {
    return x / (1.0f + fabsf(x)) * 0.5f + 0.5f;
}
// Native RNE bf16 converts (v_cvt_pk_bf16_f32).
__device__ __forceinline__ unsigned int f2bf2(float a, float b) {
    __hip_bfloat162 h = __float22bfloat162_rn(make_float2(a, b));
    unsigned int u; __builtin_memcpy(&u, &h, 4); return u;
}
__device__ __forceinline__ unsigned short f2bf(float f) {
    __hip_bfloat16 h = __float2bfloat16(f);
    unsigned short u; __builtin_memcpy(&u, &h, 2); return u;
}

// 16x16x16 bf16 MFMA. Fallback: zero-extend BOTH operands with the SAME
// K-permutation into the x32 op — dead products are 0*0, result identical.
__device__ __forceinline__ f32x4 mfma16(bf16x4 a, bf16x4 b, f32x4 c) {
#if __has_builtin(__builtin_amdgcn_mfma_f32_16x16x16bf16_1k)
    return __builtin_amdgcn_mfma_f32_16x16x16bf16_1k(a, b, c, 0, 0, 0);
#else
    bf16x8 a8 = {a[0], a[1], a[2], a[3], 0, 0, 0, 0};
    bf16x8 b8 = {b[0], b[1], b[2], b[3], 0, 0, 0, 0};
    return __builtin_amdgcn_mfma_f32_16x16x32_bf16(a8, b8, c, 0, 0, 0);
#endif
}

// A-frag from a row-major RS-stride slot, or B-frag from a col-major slot:
// both are elems [col*RS + quad*4 .. +3]. 8 B aligned (RS*2=40, SLOT*2=640).
__device__ __forceinline__ bf16x4 ldfrag4(const unsigned short* base, int lane) {
    return *(const bf16x4*)(base + (lane & 15) * RS + (lane >> 4) * 4);
}
// Same from a packed global 16x16 matrix (stride 16): rm matrix -> A-frag,
// cm matrix -> B-frag.
__device__ __forceinline__ bf16x4 ldfrag_g4(const unsigned short* base, int lane) {
    return *(const bf16x4*)(base + (lane & 15) * 16 + (lane >> 4) * 4);
}
// D-fragment -> B-fragment is the identity lane mapping for 16x16 shapes.
__device__ __forceinline__ bf16x4 cvt4(f32x4 d) {
    union { unsigned int u[2]; bf16x4 v; } cv;
    cv.u[0] = f2bf2(d[0], d[1]);
    cv.u[1] = f2bf2(d[2], d[3]);
    return cv.v;
}
__device__ __forceinline__ void store16(unsigned short* slot, f32x4 d, int lane, bool odd) {
    int col = lane & 15, quad = lane >> 4;
    if (odd) {  // col-major (B-ready): packed 8 B store
        ull pk = (ull)f2bf2(d[0], d[1]) | ((ull)f2bf2(d[2], d[3]) << 32);
        *(ull*)(slot + col * RS + quad * 4) = pk;
    } else {    // row-major (A-ready): 4-elem scatter
#pragma unroll
        for (int r = 0; r < 4; r++) slot[(quad * 4 + r) * RS + col] = f2bf(d[r]);
    }
}

// lv2..root of a 16-input tree: 8 inputs row-major in LDS at slots 8w and 8w+4,
// 8 inputs reg-fed (B1a, B1b; D==B layout). ONE barrier; lv4+root on wave 0
// only (root is only consumed by w0). Waves 1-3 return garbage and are free to
// run ahead — callers must not let them write slots before their next
// __syncthreads (chunk: next softmax barrier; reduce: they exit).
__device__ __forceinline__ f32x4 tree_upper(unsigned short* slots, int lane, int w,
                                            bf16x4 B1a, bf16x4 B1b) {
    f32x4 z = {0.f, 0.f, 0.f, 0.f};
    f32x4 dA = mfma16(ldfrag4(slots + (8 * w) * SLOT, lane), B1a, z);   // lv2 prod 2w
    store16(slots + (8 * w) * SLOT, dA, lane, false);                   // -> A of lv3
    f32x4 dB = mfma16(ldfrag4(slots + (8 * w + 4) * SLOT, lane), B1b, z); // lv2 prod 2w+1
    f32x4 d3 = mfma16(ldfrag4(slots + (8 * w) * SLOT, lane), cvt4(dB), z); // lv3 prod w
    store16(slots + (8 * w) * SLOT, d3, lane, w & 1);  // w0:s0 rm, w1:s8 cm, w2:s16 rm, w3:s24 cm
    __syncthreads();
    f32x4 root = z;
    if (w == 0) {
        f32x4 d4a = mfma16(ldfrag4(slots, lane), ldfrag4(slots + 8 * SLOT, lane), z);
        f32x4 d4b = mfma16(ldfrag4(slots + 16 * SLOT, lane), ldfrag4(slots + 24 * SLOT, lane), z);
        store16(slots, d4a, lane, false);              // rm -> A of root (same-wave, lgkm-ordered)
        root = mfma16(ldfrag4(slots, lane), cvt4(d4b), z);
    }
    return root;
}

// 64 blocks: every block redundantly normalizes T in LDS (cheap), then block cc
// computes TTT[.][cc] = (T_c * T_{c'}) column. Block 0 also writes init/acc.
__global__ void __launch_bounds__(256) prepall_kernel(const float* __restrict__ invh_init,
                                                      const float* __restrict__ invh_T,
                                                      const float* __restrict__ invh_acc,
                                                      unsigned char* __restrict__ wsb) {
    __shared__ float Tn[2048];  // Tn[(p*8+c)*16 + n]
    int t = threadIdx.x;  // 256
    int cc = blockIdx.x, c = cc >> 3, c2 = cc & 7;
    if (t < S * C) {
        float v[S]; float s = 0.f;
#pragma unroll
        for (int n = 0; n < S; n++) { v[n] = hsig(invh_T[t * S + n]); s += v[n]; }
        float inv = 1.f / s;
#pragma unroll
        for (int n = 0; n < S; n++) Tn[t * S + n] = v[n] * inv;
    }
    __syncthreads();
    int p = t >> 4, n = t & 15;
    float a = 0.f;
#pragma unroll
    for (int k = 0; k < S; k++) a += Tn[(p * 8 + c) * 16 + k] * Tn[(k * 8 + c2) * 16 + n];
    ((unsigned short*)(wsb + WS_TTT))[t * 64 + cc] = f2bf(a);

    if (cc == 0 && t < S) {
        float s = 0.f;
#pragma unroll
        for (int k = 0; k < S; k++) s += hsig(invh_init[k]);
        ((float*)(wsb + WS_INIT))[t] = hsig(invh_init[t]) / s;
        ((float*)(wsb + WS_ACC))[t] = logf(hsig(invh_acc[t]));
    }
}

// Four chunks per block, combined in-block to ONE quad matrix (roots r0..r3
// held in VGPRs, combined w0-only at the end). 1024 blocks = 4/CU, fully
// resident in a single scheduling round. Each ch's softmax barrier orders the
// previous ch's w0 slot reads before the next construct's slot writes.
__global__ void __launch_bounds__(256) chunk_kernel(const float* __restrict__ logx,
                                                    unsigned char* __restrict__ wsb) {
    __shared__ __align__(16) unsigned short slots[32 * SLOT];  // 20480 B
    __shared__ __align__(16) float xs[LC * XSS];               // 2560 B normalized probs
    __shared__ float clpart[4];

    int tid = threadIdx.x, lane = tid & 63, w = tid >> 6;
    int col = lane & 15, quad = lane >> 4;
    int qi = blockIdx.x, b = blockIdx.y;
    int chunk0 = 4 * qi;

    // B-frags for the pair-product construct (wave w owns p-tiles 4w..4w+3).
    const unsigned short* TTT = (const unsigned short*)(wsb + WS_TTT);
    bf16x8 bfr[4][2];
#pragma unroll
    for (int jj = 0; jj < 4; jj++) {
        int t = 4 * w + jj;
#pragma unroll
        for (int kk = 0; kk < 2; kk++)
            bfr[jj][kk] = *(const bf16x8*)(TTT + (t * 16 + col) * 64 + kk * 32 + quad * 8);
    }

    // All four chunks' x tiles: issue global loads now (latency hidden under setup).
    const float* xg = logx + ((size_t)b * L + (size_t)chunk0 * LC) * C;
    float2 vv0 = *(const float2*)(xg + 2 * tid);
    float2 vv1 = *(const float2*)(xg + 1 * LC * C + 2 * tid);
    float2 vv2 = *(const float2*)(xg + 2 * LC * C + 2 * tid);
    float2 vv3 = *(const float2*)(xg + 3 * LC * C + 2 * tid);

    f32x4 r0, r1, r2, r3;
#pragma unroll
    for (int ch = 0; ch < 4; ch++) {
        int chunk = chunk0 + ch;

        // Per-step softmax: thread tid owns channels {2(tid&3), 2(tid&3)+1} of
        // step tid>>2; 4-lane-group shuffle reduce.
        float2 v = (ch == 0) ? vv0 : (ch == 1) ? vv1 : (ch == 2) ? vv2 : vv3;
        float m = fmaxf(v.x, v.y);
        m = fmaxf(m, __shfl_xor(m, 1));
        m = fmaxf(m, __shfl_xor(m, 2));
        float e0 = __expf(v.x - m), e1 = __expf(v.y - m);
        float s = e0 + e1;
        s += __shfl_xor(s, 1);
        s += __shfl_xor(s, 2);
        float inv = 1.0f / s;
        *(float2*)(xs + (tid >> 2) * XSS + 2 * (tid & 3)) = make_float2(e0 * inv, e1 * inv);
        float lx = ((tid & 3) == 0) ? (m + __logf(s)) : 0.f;   // one contribution per step
#pragma unroll
        for (int d = 1; d < 64; d <<= 1) lx += __shfl_xor(lx, d);  // wave partial (16 steps)
        if (lane == 0) clpart[w] = lx;
        __syncthreads();   // orders prev-ch w0 slot reads before this ch's slot writes
        if (tid == 0)
            ((float*)(wsb + WS_CLOG))[b * K + chunk] = clpart[0] + clpart[1] + clpart[2] + clpart[3];

        // A-frags: y[i][cc'] = xn[2i][c]*xn[2i+1][c'].
        bf16x8 afr[2][2];
#pragma unroll
        for (int mt = 0; mt < 2; mt++) {
            int i2 = 2 * (mt * 16 + col);
            const float2* x1p = (const float2*)(xs + (i2 + 1) * XSS);
            float2 q0 = x1p[0], q1 = x1p[1], q2 = x1p[2], q3 = x1p[3];
#pragma unroll
            for (int kk = 0; kk < 2; kk++) {
                float x0 = xs[i2 * XSS + kk * 4 + quad];
                union { unsigned int u[4]; bf16x8 v8; } cv;
                cv.u[0] = f2bf2(x0 * q0.x, x0 * q0.y);
                cv.u[1] = f2bf2(x0 * q1.x, x0 * q1.y);
                cv.u[2] = f2bf2(x0 * q2.x, x0 * q2.y);
                cv.u[3] = f2bf2(x0 * q3.x, x0 * q3.y);
                afr[mt][kk] = cv.v8;
            }
        }

        // Pair-product construct -> slots 0..31 (parity i&1: even rm / odd cm).
#pragma unroll
        for (int mt = 0; mt < 2; mt++)
#pragma unroll
            for (int jj = 0; jj < 4; jj++) {
                f32x4 acc = {0.f, 0.f, 0.f, 0.f};
#pragma unroll
                for (int kk = 0; kk < 2; kk++)
                    acc = __builtin_amdgcn_mfma_f32_16x16x32_bf16(afr[mt][kk], bfr[jj][kk], acc, 0, 0, 0);
                int t = 4 * w + jj;  // = p
#pragma unroll
                for (int r = 0; r < 4; r++) {
                    int i = mt * 16 + quad * 4 + r;
                    int off = (i & 1) ? (col * RS + t) : (t * RS + col);
                    slots[i * SLOT + off] = f2bf(acc[r]);
                }
            }
        __syncthreads();

        // lv1: wave w owns products i in [4w,4w+4). Even i -> LDS (A of lv2),
        // odd i -> registers (B of lv2, D==B layout).
        bf16x4 B1[2];
        {
            f32x4 z = {0.f, 0.f, 0.f, 0.f};
#pragma unroll
            for (int i2 = 0; i2 < 4; i2++) {
                int i = 4 * w + i2;
                f32x4 d = mfma16(ldfrag4(slots + (2 * i) * SLOT, lane),
                                 ldfrag4(slots + (2 * i + 1) * SLOT, lane), z);
                if (i2 & 1) B1[i2 >> 1] = cvt4(d);
                else store16(slots + (2 * i) * SLOT, d, lane, false);
            }
        }
        f32x4 root = tree_upper(slots, lane, w, B1[0], B1[1]);  // valid on w0 only
        if (ch == 0) r0 = root; else if (ch == 1) r1 = root;
        else if (ch == 2) r2 = root; else r3 = root;
    }

    // In-block quad combine (w0 only; waves 1-3 have exited their slot reads).
    // Order: ((r0*r1)*(r2*r3)) == r0*r1*r2*r3 (left-to-right chain).
    if (w == 0) {
        f32x4 z = {0.f, 0.f, 0.f, 0.f};
        store16(slots, r0, lane, false);               // rm -> A (same-wave ordered)
        f32x4 p01 = mfma16(ldfrag4(slots, lane), cvt4(r1), z);
        store16(slots + 8 * SLOT, r2, lane, false);
        f32x4 p23 = mfma16(ldfrag4(slots + 8 * SLOT, lane), cvt4(r3), z);
        store16(slots, p01, lane, false);              // WAR same-wave: read done before write
        f32x4 fin = mfma16(ldfrag4(slots, lane), cvt4(p23), z);
        unsigned short* cp = (unsigned short*)(wsb + WS_CP) + ((size_t)b * NQ + qi) * 256;
        if (qi & 1) {  // cm (B-frag-ready for reduce)
            ull pk = (ull)f2bf2(fin[0], fin[1]) | ((ull)f2bf2(fin[2], fin[3]) << 32);
            *(ull*)(cp + col * 16 + quad * 4) = pk;
        } else {       // rm (A-frag-ready for reduce)
#pragma unroll
            for (int r = 0; r < 4; r++) cp[(quad * 4 + r) * 16 + col] = f2bf(fin[r]);
        }
    }
}

// 16 quad-matrices per batch feed tree_upper directly: wave w copies even
// inputs 4w+0 / 4w+2 (rm in global) into slots 8w / 8w+4 (A-frag positions),
// loads odd inputs 4w+1 / 4w+3 (cm in global) as reg B-frags. No lv0 MFMAs.
__global__ void __launch_bounds__(256) reduce_kernel(unsigned char* __restrict__ wsb,
                                                     float* __restrict__ out) {
    __shared__ __align__(16) unsigned short slots[32 * SLOT];  // 20480 B
    int tid = threadIdx.x, lane = tid & 63, w = tid >> 6;
    int col = lane & 15, quad = lane >> 4;
    int b = blockIdx.x;

    const unsigned short* cpb = (const unsigned short*)(wsb + WS_CP) + (size_t)b * NQ * 256;
    bf16x4 e0 = ldfrag_g4(cpb + (size_t)(4 * w + 0) * 256, lane);  // rm -> A-frag
    bf16x4 e1 = ldfrag_g4(cpb + (size_t)(4 * w + 2) * 256, lane);
    bf16x4 B1a = ldfrag_g4(cpb + (size_t)(4 * w + 1) * 256, lane); // cm -> B-frag
    bf16x4 B1b = ldfrag_g4(cpb + (size_t)(4 * w + 3) * 256, lane);
    *(bf16x4*)(slots + (8 * w) * SLOT + col * RS + quad * 4) = e0;      // A-frag positions
    *(bf16x4*)(slots + (8 * w + 4) * SLOT + col * RS + quad * 4) = e1;
    f32x4 troot = tree_upper(slots, lane, w, B1a, B1b);

    if (w == 0) {
        const float* initp = (const float*)(wsb + WS_INIT);
        const float* acclog = (const float*)(wsb + WS_ACC);
        float part = 0.f;
#pragma unroll
        for (int r = 0; r < 4; r++) part += initp[quad * 4 + r] * troot[r];
        part += __shfl_xor(part, 16);
        part += __shfl_xor(part, 32);
        float lp = logf(fmaxf(part, 0.f) + 1e-30f) + acclog[col];
        float mx = lp;
#pragma unroll
        for (int d = 1; d < 16; d <<= 1) mx = fmaxf(mx, __shfl_xor(mx, d));
        float a2 = isfinite(mx) ? mx : 0.0f;  // jax.nn.logsumexp semantics
        float sm = expf(lp - a2);
#pragma unroll
        for (int d = 1; d < 16; d <<= 1) sm += __shfl_xor(sm, d);
        float cl = ((const float*)(wsb + WS_CLOG))[b * K + lane];
#pragma unroll
        for (int d = 1; d < 64; d <<= 1) cl += __shfl_xor(cl, d);
        if (lane == 0) out[b] = logf(sm) + a2 + cl;
    }
}

extern "C" void kernel_launch(void* const* d_in, const int* in_sizes, int n_in,
                              void* d_out, int out_size, void* d_ws, size_t ws_size,
                              hipStream_t stream) {
    const float* logx = (const float*)d_in[0];   // (B, L, C) f32
    const float* init = (const float*)d_in[1];   // (S,) f32
    const float* T    = (const float*)d_in[2];   // (S, C, S) f32
    const float* acc  = (const float*)d_in[3];   // (S,) f32
    unsigned char* wsb = (unsigned char*)d_ws;
    float* out = (float*)d_out;

    prepall_kernel<<<64, 256, 0, stream>>>(init, T, acc, wsb);
    chunk_kernel<<<dim3(NQ, NB), 256, 0, stream>>>(logx, wsb);
    reduce_kernel<<<NB, 256, 0, stream>>>(wsb, out);
}